// Round 13
// baseline (2991.001 us; speedup 1.0000x reference)
//
#include <hip/hip_runtime.h>

typedef _Float16 f16;
typedef __attribute__((ext_vector_type(4))) _Float16 f16x4;
typedef __attribute__((ext_vector_type(8))) _Float16 f16x8;
typedef __attribute__((ext_vector_type(16))) float f32x16;

#define MT 128           // batch rows per block
#define NBF 4
#define LDSP 1024        // act row pitch bytes (512 f16)
#define SLOT 8192        // ring slot bytes (one half-kf chunk = 8 frags)

#define OFF2 0
#define OFF3 32768
#define OFF4 163840
#define OFF5 425984
#define OFF6 688128
#define OFF7 950272
#define OFF8 1081344
#define OFF9 1114112
#define TOTAL_FRAG_LANES 139776

__device__ __forceinline__ uint32_t swz(int row, int colbytes) {
  return (uint32_t)(row * LDSP + (colbytes ^ ((row & 31) << 4)));
}

// weight repack: fp32 [K][N] -> fp16 A-fragment order (1 KiB per 32x16 frag,
// frag-major => chunk c of a layer = bytes [c*8192, +8192) = frags 8c..8c+7).
__global__ void repack_kernel(const float* __restrict__ W2, const float* __restrict__ W3,
                              const float* __restrict__ W4, const float* __restrict__ W5,
                              const float* __restrict__ W6, const float* __restrict__ W7,
                              const float* __restrict__ W8, const float* __restrict__ W9,
                              f16* __restrict__ ws) {
  int gid = blockIdx.x * 256 + threadIdx.x;
  if (gid >= TOTAL_FRAG_LANES) return;
  const float* src; int N, NT; size_t dst; int local;
  if      (gid <   4096) { src = W2; N = 256; NT = 8;  dst = OFF2; local = gid;          }
  else if (gid <  20480) { src = W3; N = 512; NT = 16; dst = OFF3; local = gid -   4096; }
  else if (gid <  53248) { src = W4; N = 512; NT = 16; dst = OFF4; local = gid -  20480; }
  else if (gid <  86016) { src = W5; N = 512; NT = 16; dst = OFF5; local = gid -  53248; }
  else if (gid < 118784) { src = W6; N = 512; NT = 16; dst = OFF6; local = gid -  86016; }
  else if (gid < 135168) { src = W7; N = 256; NT = 8;  dst = OFF7; local = gid - 118784; }
  else if (gid < 139264) { src = W8; N = 128; NT = 4;  dst = OFF8; local = gid - 135168; }
  else                   { src = W9; N = 3;   NT = 1;  dst = OFF9; local = gid - 139264; }
  int lane = local & 63;
  int frag = local >> 6;
  int kf = frag / NT, nf = frag % NT;
  int n  = nf * 32 + (lane & 31);
  int kb = kf * 16 + ((lane >> 5) << 3);
  f16x8 v;
  #pragma unroll
  for (int i = 0; i < 8; ++i) {
    float val = (n < N) ? src[(size_t)(kb + i) * N + n] : 0.0f;
    v[i] = (f16)val;
  }
  *reinterpret_cast<f16x8*>(ws + dst + (size_t)local * 8) = v;
}

__device__ __forceinline__ void gload16(const f16* g, char* l) {
  __builtin_amdgcn_global_load_lds(
      (const __attribute__((address_space(1))) void*)g,
      (__attribute__((address_space(3))) void*)l, 16, 0, 0);
}

// Cooperative 8KiB chunk stage: 512 threads x 16B, frag-linear.
__device__ __forceinline__ void stage8k(const f16* __restrict__ src, char* slotbase, int tid) {
  const int lane = tid & 63, wid = tid >> 6;
  gload16(src + (size_t)(wid * 64 + lane) * 8, slotbase + wid * 1024);
}

// Ring-staged layer with ENFORCED ANTI-PHASE:
//  MF=16: chunk (kf,hh) is consumed only by waves {hh*4..hh*4+3}; waves w and
//  w+4 share a SIMD -> per phase each SIMD has one MFMA wave + one load wave.
//  Per phase: barrier; stage(c+3); vmcnt(2) [2 chunks always in flight];
//  active: lgkm(0)+sched_barrier+setprio+8 MFMA; next-active: ds_read operands.
template<int KT, int MF>
__device__ __forceinline__ void run_ring(char* act, char* ring,
    const f16* __restrict__ wp, const f16* __restrict__ wp_next,
    const float* __restrict__ bias, int tid) {
  constexpr int NP = KT * MF / 8;   // phases (chunks); always %4==0
  constexpr int FM = MF / 8;        // 2 (wide) or 1
  const int lane = tid & 63, wid = tid >> 6;
  const int mlane = lane & 31, h = lane >> 5;
  const int hh = wid >> 2;          // phase-parity group
  const uint32_t l16 = (uint32_t)lane * 16;
  const uint32_t woff = (MF == 16) ? (uint32_t)(wid & 3) * 2048 : (uint32_t)wid * 1024;

  f32x16 acc[FM][4];
  #pragma unroll
  for (int fm = 0; fm < FM; ++fm) {
    const int mbase = (wid * FM + fm) * 32;
    #pragma unroll
    for (int g = 0; g < 4; ++g) {
      const float4 bb = *reinterpret_cast<const float4*>(&bias[mbase + g * 8 + 4 * h]);
      #pragma unroll
      for (int j = 0; j < 4; ++j)
        #pragma unroll
        for (int fb = 0; fb < 4; ++fb)
          acc[fm][fb][g * 4 + j] = ((const float*)&bb)[j];
    }
  }

  uint32_t rbase[4], rx[4];
  #pragma unroll
  for (int fb = 0; fb < 4; ++fb) {
    int row = fb * 32 + mlane;
    rbase[fb] = (uint32_t)row * LDSP;
    rx[fb] = (uint32_t)((row & 31) << 4);
  }

  f16x8 rw0, rw1, rb0, rb1, rb2, rb3;
#define BREADS(KF)                                                             \
  rb0 = *reinterpret_cast<const f16x8*>(act + rbase[0] + (((uint32_t)((KF) * 32 + h * 16)) ^ rx[0])); \
  rb1 = *reinterpret_cast<const f16x8*>(act + rbase[1] + (((uint32_t)((KF) * 32 + h * 16)) ^ rx[1])); \
  rb2 = *reinterpret_cast<const f16x8*>(act + rbase[2] + (((uint32_t)((KF) * 32 + h * 16)) ^ rx[2])); \
  rb3 = *reinterpret_cast<const f16x8*>(act + rbase[3] + (((uint32_t)((KF) * 32 + h * 16)) ^ rx[3]))

  { // prologue operand read: my first active chunk ((MF==16)?hh:0), kf=0
    const char* slot = ring + (uint32_t)((MF == 16) ? hh : 0) * SLOT;
    rw0 = *reinterpret_cast<const f16x8*>(slot + woff + l16);
    if constexpr (MF == 16)
      rw1 = *reinterpret_cast<const f16x8*>(slot + woff + 1024 + l16);
    BREADS(0);
  }

  #pragma unroll 1
  for (int c = 0; c < NP; ++c) {
    __builtin_amdgcn_s_barrier();
    const int sc = c + 3;
    const f16* src = (sc < NP) ? (wp + (size_t)sc * 4096)
                               : (wp_next + (size_t)(sc - NP) * 4096);
    stage8k(src, ring + (uint32_t)(sc & 3) * SLOT, tid);
    asm volatile("s_waitcnt vmcnt(2)" ::: "memory");   // chunk c landed; c+1..c+3 in flight
    const bool act_now = (MF == 8) || ((c & 1) == hh);
    if (act_now) {
      asm volatile("s_waitcnt lgkmcnt(0)" ::: "memory");
      __builtin_amdgcn_sched_barrier(0);
      __builtin_amdgcn_s_setprio(1);
      acc[0][0] = __builtin_amdgcn_mfma_f32_32x32x16_f16(rw0, rb0, acc[0][0], 0, 0, 0);
      acc[0][1] = __builtin_amdgcn_mfma_f32_32x32x16_f16(rw0, rb1, acc[0][1], 0, 0, 0);
      acc[0][2] = __builtin_amdgcn_mfma_f32_32x32x16_f16(rw0, rb2, acc[0][2], 0, 0, 0);
      acc[0][3] = __builtin_amdgcn_mfma_f32_32x32x16_f16(rw0, rb3, acc[0][3], 0, 0, 0);
      if constexpr (FM == 2) {
        acc[1][0] = __builtin_amdgcn_mfma_f32_32x32x16_f16(rw1, rb0, acc[1][0], 0, 0, 0);
        acc[1][1] = __builtin_amdgcn_mfma_f32_32x32x16_f16(rw1, rb1, acc[1][1], 0, 0, 0);
        acc[1][2] = __builtin_amdgcn_mfma_f32_32x32x16_f16(rw1, rb2, acc[1][2], 0, 0, 0);
        acc[1][3] = __builtin_amdgcn_mfma_f32_32x32x16_f16(rw1, rb3, acc[1][3], 0, 0, 0);
      }
      __builtin_amdgcn_s_setprio(0);
    }
    const int cn = c + 1;
    if (cn < NP && ((MF == 8) || ((cn & 1) == hh))) {
      const char* slot = ring + (uint32_t)(cn & 3) * SLOT;
      const int kfn = (MF == 16) ? (cn >> 1) : cn;
      rw0 = *reinterpret_cast<const f16x8*>(slot + woff + l16);
      if constexpr (MF == 16)
        rw1 = *reinterpret_cast<const f16x8*>(slot + woff + 1024 + l16);
      BREADS(kfn);
    }
  }
#undef BREADS

  __syncthreads();   // all act reads done (also drains tail DMA)
  #pragma unroll
  for (int fm = 0; fm < FM; ++fm) {
    const int mbase = (wid * FM + fm) * 32;
    #pragma unroll
    for (int fb = 0; fb < 4; ++fb) {
      const int row = fb * 32 + mlane;
      #pragma unroll
      for (int g = 0; g < 4; ++g) {
        const int m0 = mbase + g * 8 + 4 * h;
        f16x4 v;
        #pragma unroll
        for (int j = 0; j < 4; ++j)
          v[j] = (f16)fmaxf(acc[fm][fb][g * 4 + j], 0.0f);
        *reinterpret_cast<f16x4*>(act + swz(row, m0 * 2)) = v;
      }
    }
  }
  __syncthreads();
}

// small-layer direct path (L8)
template<int KT, int MF, int WMG, int WBG>
__device__ __forceinline__ void run_direct(char* act, const f16* __restrict__ wp,
                                           const float* __restrict__ bias, int tid) {
  constexpr int FM = MF / WMG, FB = NBF / WBG;
  const int lane = tid & 63, wid = tid >> 6;
  const int wm = wid / WBG, wb = wid % WBG;
  const int mlane = lane & 31, h = lane >> 5;
  f32x16 acc[FM][FB];
  #pragma unroll
  for (int fm = 0; fm < FM; ++fm) {
    const int mbase = (wm * FM + fm) * 32;
    #pragma unroll
    for (int g = 0; g < 4; ++g) {
      const float4 bb = *reinterpret_cast<const float4*>(&bias[mbase + g * 8 + 4 * h]);
      #pragma unroll
      for (int j = 0; j < 4; ++j)
        #pragma unroll
        for (int fb = 0; fb < FB; ++fb)
          acc[fm][fb][g * 4 + j] = ((const float*)&bb)[j];
    }
  }
  const f16x8* __restrict__ wfrag = reinterpret_cast<const f16x8*>(wp);
  #pragma unroll 2
  for (int kf = 0; kf < KT; ++kf) {
    f16x8 a[FM];
    #pragma unroll
    for (int fm = 0; fm < FM; ++fm)
      a[fm] = wfrag[(size_t)(kf * MF + wm * FM + fm) * 64 + lane];
    f16x8 b[FB];
    #pragma unroll
    for (int fb = 0; fb < FB; ++fb)
      b[fb] = *reinterpret_cast<const f16x8*>(
          act + swz((wb * FB + fb) * 32 + mlane, kf * 32 + h * 16));
    #pragma unroll
    for (int fm = 0; fm < FM; ++fm)
      #pragma unroll
      for (int fb = 0; fb < FB; ++fb)
        acc[fm][fb] = __builtin_amdgcn_mfma_f32_32x32x16_f16(a[fm], b[fb], acc[fm][fb], 0, 0, 0);
  }
  __syncthreads();
  #pragma unroll
  for (int fm = 0; fm < FM; ++fm) {
    const int mbase = (wm * FM + fm) * 32;
    #pragma unroll
    for (int fb = 0; fb < FB; ++fb) {
      const int row = (wb * FB + fb) * 32 + mlane;
      #pragma unroll
      for (int g = 0; g < 4; ++g) {
        const int m0 = mbase + g * 8 + 4 * h;
        f16x4 v;
        #pragma unroll
        for (int j = 0; j < 4; ++j)
          v[j] = (f16)fmaxf(acc[fm][fb][g * 4 + j], 0.0f);
        *reinterpret_cast<f16x4*>(act + swz(row, m0 * 2)) = v;
      }
    }
  }
  __syncthreads();
}

__global__ __launch_bounds__(512, 2)
void mlp_kernel(const float* __restrict__ x,
                const float* __restrict__ W1, const float* __restrict__ b1,
                const f16*   __restrict__ wpk,
                const float* __restrict__ b2, const float* __restrict__ b3,
                const float* __restrict__ b4, const float* __restrict__ b5,
                const float* __restrict__ b6, const float* __restrict__ b7,
                const float* __restrict__ b8, const float* __restrict__ b9,
                float* __restrict__ out) {
  __shared__ __align__(16) char act[MT * LDSP];   // 128 KiB
  __shared__ __align__(16) char ring[4 * SLOT];   // 32 KiB, 4 chunk slots
  const int row0 = blockIdx.x * MT;
  const int tid  = threadIdx.x;
  const int lane = tid & 63, wid = tid >> 6;

  // stage L2 chunks 0..2 (land during L1; drained by L1's syncthreads)
  stage8k(wpk + OFF2,        ring,            tid);
  stage8k(wpk + OFF2 + 4096, ring + SLOT,     tid);
  stage8k(wpk + OFF2 + 8192, ring + 2 * SLOT, tid);

  // ---- Layer 1: 2 -> 128, fp32 VALU ----
  {
    const int r  = tid >> 2;
    const int cb = (tid & 3) * 32;
    const float2 xv = reinterpret_cast<const float2*>(x)[row0 + r];
    #pragma unroll
    for (int q = 0; q < 4; ++q) {
      f16x8 v;
      #pragma unroll
      for (int j = 0; j < 8; ++j) {
        int c = cb + q * 8 + j;
        v[j] = (f16)fmaxf(fmaf(xv.y, W1[128 + c], fmaf(xv.x, W1[c], b1[c])), 0.0f);
      }
      *reinterpret_cast<f16x8*>(act + swz(r, cb * 2 + q * 16)) = v;
    }
  }
  __syncthreads();   // act ready; chunks 0..2 landed, 0 in flight

  run_ring<8,  8 >(act, ring, wpk + OFF2, wpk + OFF3, b2, tid);   // 128->256
  run_ring<16, 16>(act, ring, wpk + OFF3, wpk + OFF4, b3, tid);   // 256->512
  #pragma unroll 1
  for (int rep = 0; rep < 3; ++rep) {   // L4-L6: 512->512
    const float* bias = (rep == 0) ? b4 : (rep == 1) ? b5 : b6;
    const f16* wp = wpk + OFF4 + rep * (OFF5 - OFF4);
    run_ring<32, 16>(act, ring, wp, wp + (OFF5 - OFF4), bias, tid);  // rep==2 next == OFF7
  }
  run_ring<32, 8 >(act, ring, wpk + OFF7, wpk + OFF8, b7, tid);   // 512->256 (tail stages L8 bytes, unread)
  run_direct<16, 4, 4, 2>(act, wpk + OFF8, b8, tid);              // 256->128

  // ---- Layer 9: 128 -> 3 (padded 32), sigmoid ----
  if (wid < 4) {
    const int mlane = lane & 31;
    const int h     = lane >> 5;
    f32x16 acc = (f32x16)0.0f;
    const f16x8* __restrict__ wfrag = reinterpret_cast<const f16x8*>(wpk + OFF9);
    #pragma unroll
    for (int kf = 0; kf < 8; ++kf) {
      f16x8 a = wfrag[(size_t)kf * 64 + lane];
      f16x8 b = *reinterpret_cast<const f16x8*>(
          act + swz(wid * 32 + mlane, kf * 32 + h * 16));
      acc = __builtin_amdgcn_mfma_f32_32x32x16_f16(a, b, acc, 0, 0, 0);
    }
    if (h == 0) {
      const size_t orow = (size_t)(row0 + wid * 32 + mlane) * 3;
      #pragma unroll
      for (int r = 0; r < 3; ++r) {
        float v = acc[r] + b9[r];
        out[orow + r] = 1.0f / (1.0f + __expf(-v));
      }
    }
  }
}

extern "C" void kernel_launch(void* const* d_in, const int* in_sizes, int n_in,
                              void* d_out, int out_size, void* d_ws, size_t ws_size,
                              hipStream_t stream) {
  const float* x  = (const float*)d_in[0];
  const float* W1 = (const float*)d_in[1];  const float* b1 = (const float*)d_in[2];
  const float* W2 = (const float*)d_in[3];  const float* b2 = (const float*)d_in[4];
  const float* W3 = (const float*)d_in[5];  const float* b3 = (const float*)d_in[6];
  const float* W4 = (const float*)d_in[7];  const float* b4 = (const float*)d_in[8];
  const float* W5 = (const float*)d_in[9];  const float* b5 = (const float*)d_in[10];
  const float* W6 = (const float*)d_in[11]; const float* b6 = (const float*)d_in[12];
  const float* W7 = (const float*)d_in[13]; const float* b7 = (const float*)d_in[14];
  const float* W8 = (const float*)d_in[15]; const float* b8 = (const float*)d_in[16];
  const float* W9 = (const float*)d_in[17]; const float* b9 = (const float*)d_in[18];
  f16* wpk = (f16*)d_ws;

  repack_kernel<<<(TOTAL_FRAG_LANES + 255) / 256, 256, 0, stream>>>(
      W2, W3, W4, W5, W6, W7, W8, W9, wpk);

  mlp_kernel<<<1048576 / MT, 512, 0, stream>>>(
      x, W1, b1, wpk, b2, b3, b4, b5, b6, b7, b8, b9, (float*)d_out);
}